// Round 5
// baseline (106.819 us; speedup 1.0000x reference)
//
#include <hip/hip_runtime.h>

#define B_N 8192
#define C_N 20000
#define D_N 128
#define CPAD 20096              // 157 * 128
#define NTILES 157
#define NSPLIT 8                // tiles strided: tile = chunk + 8*j
#define MARGIN_F 0.15001125f    // 0.15 + (1/40000)*(0.6-0.15)

#define NORM_BLOCKS 2048        // 8192 rows / 4 per block
#define CONV_BLOCKS 2512        // CPAD*128/4/256

typedef __attribute__((ext_vector_type(8))) short bf16x8;
typedef __attribute__((ext_vector_type(4))) float f32x4;

__device__ __forceinline__ unsigned short f2bf(float x) {
    union { float f; unsigned int u; } v; v.f = x;
    unsigned int r = v.u + 0x7fffu + ((v.u >> 16) & 1u);
    return (unsigned short)(r >> 16);
}
__device__ __forceinline__ float bf2f(unsigned short h) {
    union { unsigned int u; float f; } v; v.u = ((unsigned int)h) << 16; return v.f;
}

// ---- kernel 1 (fused prep): blocks [0,2048) normalize features; rest convert
// centers -> bf16 (zero-padded to CPAD rows). Per-row corrections go to arrays
// (round-3 lesson: contended same-address atomics serialize ~200us).
__global__ __launch_bounds__(256) void k_prep(
    const float* __restrict__ feat, const float* __restrict__ centers,
    const int* __restrict__ labels, unsigned short* __restrict__ fb,
    unsigned short* __restrict__ cb, float* __restrict__ t,
    float* __restrict__ corr_s, unsigned int* __restrict__ corr_c)
{
    const int bid = blockIdx.x;
    if (bid < NORM_BLOCKS) {
        const int lane = threadIdx.x & 63;
        const int row  = bid * 4 + (threadIdx.x >> 6);   // wave per row
        const float2 fv = *(const float2*)(feat + (size_t)row * D_N + lane * 2);
        float ss = fv.x * fv.x + fv.y * fv.y;
        #pragma unroll
        for (int off = 32; off; off >>= 1) ss += __shfl_xor(ss, off);
        const float scale = 1.0f / fmaxf(sqrtf(ss), 1e-12f);
        const float a = fv.x * scale, b = fv.y * scale;
        ushort2 o; o.x = f2bf(a); o.y = f2bf(b);
        *(ushort2*)(fb + (size_t)row * D_N + lane * 2) = o;

        const int lab = labels[row];
        const float2 cv = *(const float2*)(centers + (size_t)lab * D_N + lane * 2);
        float pd = a * cv.x + b * cv.y;                                         // fp32 dot
        float pb = bf2f(o.x) * bf2f(f2bf(cv.x)) + bf2f(o.y) * bf2f(f2bf(cv.y)); // bf16 dot
        #pragma unroll
        for (int off = 32; off; off >>= 1) {
            pd += __shfl_xor(pd, off);
            pb += __shfl_xor(pb, off);
        }
        if (lane == 0) {
            const float tb = MARGIN_F - pd;
            t[row] = tb;
            float cs = fmaxf(tb + pb, 0.0f);                 // label-column term
            unsigned int cc = (tb + pb > 0.0f) ? 1u : 0u;
            if (tb > 0.0f) { cs += 96.0f * tb; cc += 96u; }  // 96 zero-pad columns
            corr_s[row] = cs;
            corr_c[row] = cc;
        }
    } else {
        const int idx = (bid - NORM_BLOCKS) * 256 + threadIdx.x;
        const int e = idx * 4;
        const int row = e >> 7;
        ushort4 o;
        if (row < C_N) {
            const float4 v = *(const float4*)(centers + e);
            o.x = f2bf(v.x); o.y = f2bf(v.y); o.z = f2bf(v.z); o.w = f2bf(v.w);
        } else {
            o.x = 0; o.y = 0; o.z = 0; o.w = 0;
        }
        *(ushort4*)(cb + e) = o;
    }
}

// ---- kernel 2: main. No LDS staging, no barriers. 256 feature rows/block in
// regs (B-operand); center fragments loaded global->VGPR per ks-phase into
// banked cfr[ks] registers; consume-then-refill gives natural WAR-pipelined
// counted-vmcnt (loads for tile j+1 in flight through all of iter j).
// Grid (8,32): chunk == XCD id -> each XCD's L2 holds only its 640KB chunk.
__global__ __launch_bounds__(512, 2) void k_main(
    const unsigned short* __restrict__ fb,   // [8192][128] bf16 normalized features
    const unsigned short* __restrict__ cb,   // [20096][128] bf16 centers, zero-padded
    const float* __restrict__ t,             // [8192]
    float* __restrict__ acc_total, unsigned int* __restrict__ acc_cnt)
{
    __shared__ float sWsum[8];
    __shared__ unsigned int sWcnt[8];

    const int tid  = threadIdx.x;
    const int lane = tid & 63;
    const int w    = tid >> 6;            // wave 0..7
    const int chunk   = blockIdx.x;       // 0..7, tiles chunk + 8*j
    const int rowbase = blockIdx.y * 256; // feature row block
    const int nt = (156 - chunk) / 8 + 1; // 20 or 19

    const int wc = (w & 1) * 64;          // wave center offset in tile
    const int wf = (w >> 1) * 64;         // wave feature offset
    const int l15 = lane & 15;
    const int kg  = lane >> 4;

    // ---- feature fragments + t values -> registers (block-lifetime) ----
    bf16x8 ffr[4][4];                     // [ks][ff]
    float tvr[4];
    #pragma unroll
    for (int ff = 0; ff < 4; ++ff) {
        const int m = rowbase + wf + ff * 16 + l15;
        const unsigned short* src = fb + (size_t)m * D_N + kg * 8;
        #pragma unroll
        for (int ks = 0; ks < 4; ++ks)
            ffr[ks][ff] = *(const bf16x8*)(src + ks * 32);
        tvr[ff] = t[m];
    }

    // per-lane center offsets within a tile (elements)
    int coff[4];
    #pragma unroll
    for (int fc = 0; fc < 4; ++fc)
        coff[fc] = (wc + fc * 16 + l15) * D_N + kg * 8;

    // ---- prologue: fill all 4 ks-banks from tile j=0 ----
    bf16x8 cfr[4][4];                     // [ks][fc]
    {
        const unsigned short* nb = cb + (size_t)chunk * 128 * D_N;
        #pragma unroll
        for (int ks = 0; ks < 4; ++ks)
            #pragma unroll
            for (int fc = 0; fc < 4; ++fc)
                cfr[ks][fc] = *(const bf16x8*)(nb + coff[fc] + ks * 32);
    }

    float ls[4] = {0.0f, 0.0f, 0.0f, 0.0f};
    unsigned int wcnt = 0;

    for (int j = 0; j < nt; ++j) {
        // next tile (clamped on last iter; those loads are never consumed)
        const int jn = (j + 1 < nt) ? j + 1 : j;
        const unsigned short* pb = cb + (size_t)(chunk + 8 * jn) * 128 * D_N;

        f32x4 acc[4][4];                  // [fc][ff]
        #pragma unroll
        for (int fc = 0; fc < 4; ++fc)
            #pragma unroll
            for (int ff = 0; ff < 4; ++ff)
                #pragma unroll
                for (int r = 0; r < 4; ++r)
                    acc[fc][ff][r] = tvr[ff];

        #pragma unroll
        for (int ks = 0; ks < 4; ++ks) {
            // consume bank ks (HW waitcnt covers last iter's refill)
            #pragma unroll
            for (int fc = 0; fc < 4; ++fc)
                #pragma unroll
                for (int ff = 0; ff < 4; ++ff)
                    acc[fc][ff] = __builtin_amdgcn_mfma_f32_16x16x32_bf16(
                        cfr[ks][fc], ffr[ks][ff], acc[fc][ff], 0, 0, 0);
            // refill bank ks for next tile (in flight across rest of iter)
            #pragma unroll
            for (int fc = 0; fc < 4; ++fc)
                cfr[ks][fc] = *(const bf16x8*)(pb + coff[fc] + ks * 32);
        }

        // epilogue: loss already in acc. 3 VALU/elem + uniform SALU count.
        #pragma unroll
        for (int fc = 0; fc < 4; ++fc)
            #pragma unroll
            for (int ff = 0; ff < 4; ++ff)
                #pragma unroll
                for (int r = 0; r < 4; ++r) {
                    const float l = acc[fc][ff][r];
                    ls[fc] += fmaxf(l, 0.0f);
                    wcnt += (unsigned int)__popcll(__ballot(l > 0.0f));
                }
    }

    float lsum = (ls[0] + ls[1]) + (ls[2] + ls[3]);
    #pragma unroll
    for (int off = 32; off; off >>= 1) lsum += __shfl_xor(lsum, off);
    if (lane == 0) { sWsum[w] = lsum; sWcnt[w] = wcnt; }
    __syncthreads();
    if (tid == 0) {
        float s = 0.0f; unsigned int c = 0;
        #pragma unroll
        for (int i = 0; i < 8; ++i) { s += sWsum[i]; c += sWcnt[i]; }
        atomicAdd(acc_total, s);
        atomicAdd(acc_cnt, c);
    }
}

// ---- kernel 3: reduce corrections, finalize ----
__global__ __launch_bounds__(256) void k_finalize(
    const float* __restrict__ acc_total, const unsigned int* __restrict__ acc_cnt,
    const float* __restrict__ corr_s, const unsigned int* __restrict__ corr_c,
    float* __restrict__ out)
{
    __shared__ float ss[4];
    __shared__ unsigned int sc[4];
    const int tid = threadIdx.x;
    const int lane = tid & 63;
    const int w = tid >> 6;
    float cs = 0.0f; unsigned int cc = 0;
    for (int i = tid; i < B_N; i += 256) { cs += corr_s[i]; cc += corr_c[i]; }
    #pragma unroll
    for (int off = 32; off; off >>= 1) {
        cs += __shfl_xor(cs, off);
        cc += __shfl_xor(cc, off);
    }
    if (lane == 0) { ss[w] = cs; sc[w] = cc; }
    __syncthreads();
    if (tid == 0) {
        const float S = acc_total[0] - (ss[0] + ss[1] + ss[2] + ss[3]);
        const unsigned int C = acc_cnt[0] - (sc[0] + sc[1] + sc[2] + sc[3]);
        out[0] = C ? (S / (float)C) : 0.0f;
    }
}

extern "C" void kernel_launch(void* const* d_in, const int* in_sizes, int n_in,
                              void* d_out, int out_size, void* d_ws, size_t ws_size,
                              hipStream_t stream) {
    const float* feat    = (const float*)d_in[0];
    const float* centers = (const float*)d_in[1];
    const int*   labels  = (const int*)d_in[2];
    float* out = (float*)d_out;

    char* ws = (char*)d_ws;
    float*          acc_total = (float*)ws;                          // 4 B
    unsigned int*   acc_cnt   = (unsigned int*)(ws + 4);             // 4 B
    float*          t         = (float*)(ws + 1024);                 // 32 KB
    float*          corr_s    = (float*)(ws + 65536);                // 32 KB
    unsigned int*   corr_c    = (unsigned int*)(ws + 98304);         // 32 KB
    unsigned short* fb        = (unsigned short*)(ws + 131072);      // 2 MB
    unsigned short* cb        = (unsigned short*)(ws + 4*1024*1024); // 5.14 MB

    hipMemsetAsync(ws, 0, 8, stream);
    k_prep<<<NORM_BLOCKS + CONV_BLOCKS, 256, 0, stream>>>(
        feat, centers, labels, fb, cb, t, corr_s, corr_c);
    dim3 grid(NSPLIT, 32);
    k_main<<<grid, 512, 0, stream>>>(fb, cb, t, acc_total, acc_cnt);
    k_finalize<<<1, 256, 0, stream>>>(acc_total, acc_cnt, corr_s, corr_c, out);
}

// Round 6
// 72.356 us; speedup vs baseline: 1.4763x; 1.4763x over previous
//
#include <hip/hip_runtime.h>

#define B_N 8192
#define C_N 20000
#define D_N 128
#define CPAD 20096              // 314 * 64
#define NTILES64 314            // 64-row center tiles
#define NSPLIT 16               // tiles strided: tile = chunk + 16*j
#define MARGIN_F 0.15001125f    // 0.15 + (1/40000)*(0.6-0.15)

#define NORM_BLOCKS 2048        // 8192 rows / 4 per block
#define CONV_BLOCKS 2512        // CPAD*128/4/256

typedef __attribute__((ext_vector_type(8))) short bf16x8;
typedef __attribute__((ext_vector_type(4))) float f32x4;

typedef __attribute__((address_space(1))) const unsigned int GUint;
typedef __attribute__((address_space(3))) unsigned int LUint;

__device__ __forceinline__ unsigned short f2bf(float x) {
    union { float f; unsigned int u; } v; v.f = x;
    unsigned int r = v.u + 0x7fffu + ((v.u >> 16) & 1u);
    return (unsigned short)(r >> 16);
}
__device__ __forceinline__ float bf2f(unsigned short h) {
    union { unsigned int u; float f; } v; v.u = ((unsigned int)h) << 16; return v.f;
}

// ---- kernel 1 (fused prep): blocks [0,2048) normalize features; rest convert
// centers -> bf16 (zero-padded to CPAD rows). Per-row corrections to arrays
// (round-3 lesson: contended same-address atomics serialize ~200us).
__global__ __launch_bounds__(256) void k_prep(
    const float* __restrict__ feat, const float* __restrict__ centers,
    const int* __restrict__ labels, unsigned short* __restrict__ fb,
    unsigned short* __restrict__ cb, float* __restrict__ t,
    float* __restrict__ corr_s, unsigned int* __restrict__ corr_c)
{
    const int bid = blockIdx.x;
    if (bid < NORM_BLOCKS) {
        const int lane = threadIdx.x & 63;
        const int row  = bid * 4 + (threadIdx.x >> 6);   // wave per row
        const float2 fv = *(const float2*)(feat + (size_t)row * D_N + lane * 2);
        float ss = fv.x * fv.x + fv.y * fv.y;
        #pragma unroll
        for (int off = 32; off; off >>= 1) ss += __shfl_xor(ss, off);
        const float scale = 1.0f / fmaxf(sqrtf(ss), 1e-12f);
        const float a = fv.x * scale, b = fv.y * scale;
        ushort2 o; o.x = f2bf(a); o.y = f2bf(b);
        *(ushort2*)(fb + (size_t)row * D_N + lane * 2) = o;

        const int lab = labels[row];
        const float2 cv = *(const float2*)(centers + (size_t)lab * D_N + lane * 2);
        float pd = a * cv.x + b * cv.y;                                         // fp32 dot
        float pb = bf2f(o.x) * bf2f(f2bf(cv.x)) + bf2f(o.y) * bf2f(f2bf(cv.y)); // bf16 dot
        #pragma unroll
        for (int off = 32; off; off >>= 1) {
            pd += __shfl_xor(pd, off);
            pb += __shfl_xor(pb, off);
        }
        if (lane == 0) {
            const float tb = MARGIN_F - pd;
            t[row] = tb;
            float cs = fmaxf(tb + pb, 0.0f);                 // label-column term
            unsigned int cc = (tb + pb > 0.0f) ? 1u : 0u;
            if (tb > 0.0f) { cs += 96.0f * tb; cc += 96u; }  // 96 zero-pad columns
            corr_s[row] = cs;
            corr_c[row] = cc;
        }
    } else {
        const int idx = (bid - NORM_BLOCKS) * 256 + threadIdx.x;
        const int e = idx * 4;
        const int row = e >> 7;
        ushort4 o;
        if (row < C_N) {
            const float4 v = *(const float4*)(centers + e);
            o.x = f2bf(v.x); o.y = f2bf(v.y); o.z = f2bf(v.z); o.w = f2bf(v.w);
        } else {
            o.x = 0; o.y = 0; o.z = 0; o.w = 0;
        }
        *(ushort4*)(cb + e) = o;
    }
}

// ---- kernel 2: main. 2-phase LDS double-buffer (R2-proven), but register-
// dieted: wave tile 32 feat x 64 cent (ffr 32 + acc 32 + cfr 16 regs) so
// 4 waves/SIMD = 2 blocks/CU fit -> one block's barrier drain hides under the
// other's compute. 64-row center tiles (16 KB), prefetch issued before compute.
__global__ __launch_bounds__(512, 4) void k_main(
    const unsigned short* __restrict__ fb,   // [8192][128] bf16 normalized features
    const unsigned short* __restrict__ cb,   // [20096][128] bf16 centers, zero-padded
    const float* __restrict__ t,             // [8192]
    float* __restrict__ acc_slots)           // 4 x {sum,cnt} slots, 64B apart
{
    __shared__ __align__(16) unsigned short sB[2][64 * 128];   // 2 x 16 KB
    __shared__ float sWsum[8];
    __shared__ unsigned int sWcnt[8];

    const int tid  = threadIdx.x;
    const int lane = tid & 63;
    const int w    = tid >> 6;            // wave 0..7
    const int chunk   = blockIdx.x;       // 0..15, tiles chunk + 16*j
    const int rowbase = blockIdx.y * 256; // feature row block
    const int nt = (313 - chunk) / 16 + 1;  // 20 (chunk<10) or 19

    const int wf = w * 32;                // wave feature offset (8 groups of 32)
    const int l15 = lane & 15;
    const int kg  = lane >> 4;

    // ---- feature fragments + t values -> registers (block-lifetime) ----
    bf16x8 ffr[4][2];                     // [ks][ff]
    float tvr[2];
    #pragma unroll
    for (int ff = 0; ff < 2; ++ff) {
        const int m = rowbase + wf + ff * 16 + l15;
        const unsigned short* src = fb + (size_t)m * D_N + kg * 8;
        #pragma unroll
        for (int ks = 0; ks < 4; ++ks)
            ffr[ks][ff] = *(const bf16x8*)(src + ks * 32);
        tvr[ff] = t[m];
    }

    // ---- center staging: linear LDS dest + involution-swizzled global source ----
    const char* gB0 = (const char*)cb;
    auto STAGE = [&](int buf, int tile) {
        const char* gB = gB0 + (size_t)tile * 16384;           // 64 rows x 256 B
        const int base = w * 2048;
        #pragma unroll
        for (int i = 0; i < 2; ++i) {
            const int loff = base + i * 1024;                  // wave-uniform LDS base
            const int x = loff + lane * 16;
            const int sx = x ^ (((x >> 8) & 7) << 4);          // involution
            __builtin_amdgcn_global_load_lds((GUint*)(gB + sx),
                (LUint*)((char*)sB[buf] + loff), 16, 0, 0);
        }
    };

    STAGE(0, chunk);
    __syncthreads();

    float ls0 = 0.0f, ls1 = 0.0f;
    unsigned int wcnt = 0;

    for (int j = 0; j < nt; ++j) {
        const int cur = j & 1;
        if (j + 1 < nt) STAGE(cur ^ 1, chunk + (j + 1) * 16);  // prefetch first

        f32x4 acc[4][2];                  // [fc][ff]
        #pragma unroll
        for (int fc = 0; fc < 4; ++fc)
            #pragma unroll
            for (int ff = 0; ff < 2; ++ff)
                #pragma unroll
                for (int r = 0; r < 4; ++r)
                    acc[fc][ff][r] = tvr[ff];

        const char* sbase = (const char*)sB[cur];
        #pragma unroll
        for (int ks = 0; ks < 4; ++ks) {
            bf16x8 cfr[4];
            #pragma unroll
            for (int fc = 0; fc < 4; ++fc) {
                const int row = fc * 16 + l15;                 // center row in tile
                int p = row * 256 + ks * 64 + kg * 16;
                p ^= ((row & 7) << 4);
                cfr[fc] = *(const bf16x8*)(sbase + p);
            }
            #pragma unroll
            for (int fc = 0; fc < 4; ++fc)
                #pragma unroll
                for (int ff = 0; ff < 2; ++ff)
                    acc[fc][ff] = __builtin_amdgcn_mfma_f32_16x16x32_bf16(
                        cfr[fc], ffr[ks][ff], acc[fc][ff], 0, 0, 0);
        }

        // epilogue: loss already in acc; 3 VALU/elem + SALU ballot-count
        #pragma unroll
        for (int fc = 0; fc < 4; ++fc)
            #pragma unroll
            for (int ff = 0; ff < 2; ++ff)
                #pragma unroll
                for (int r = 0; r < 4; ++r) {
                    const float l = acc[fc][ff][r];
                    if (ff == 0) ls0 += fmaxf(l, 0.0f); else ls1 += fmaxf(l, 0.0f);
                    wcnt += (unsigned int)__popcll(__ballot(l > 0.0f));
                }

        __syncthreads();   // drains prefetch vmcnt; read buffer freed
    }

    float lsum = ls0 + ls1;
    #pragma unroll
    for (int off = 32; off; off >>= 1) lsum += __shfl_xor(lsum, off);
    if (lane == 0) { sWsum[w] = lsum; sWcnt[w] = wcnt; }
    __syncthreads();
    if (tid == 0) {
        float s = 0.0f; unsigned int c = 0;
        #pragma unroll
        for (int i = 0; i < 8; ++i) { s += sWsum[i]; c += sWcnt[i]; }
        const int slot = (blockIdx.x ^ blockIdx.y) & 3;        // spread atomics
        atomicAdd(acc_slots + slot * 16, s);
        atomicAdd((unsigned int*)(acc_slots + slot * 16 + 1), c);
    }
}

// ---- kernel 3: reduce corrections + slots, finalize ----
__global__ __launch_bounds__(256) void k_finalize(
    const float* __restrict__ acc_slots,
    const float* __restrict__ corr_s, const unsigned int* __restrict__ corr_c,
    float* __restrict__ out)
{
    __shared__ float ss[4];
    __shared__ unsigned int sc[4];
    const int tid = threadIdx.x;
    const int lane = tid & 63;
    const int w = tid >> 6;
    float cs = 0.0f; unsigned int cc = 0;
    for (int i = tid; i < B_N; i += 256) { cs += corr_s[i]; cc += corr_c[i]; }
    #pragma unroll
    for (int off = 32; off; off >>= 1) {
        cs += __shfl_xor(cs, off);
        cc += __shfl_xor(cc, off);
    }
    if (lane == 0) { ss[w] = cs; sc[w] = cc; }
    __syncthreads();
    if (tid == 0) {
        float S = -(ss[0] + ss[1] + ss[2] + ss[3]);
        long long C = -(long long)(sc[0] + sc[1] + sc[2] + sc[3]);
        #pragma unroll
        for (int i = 0; i < 4; ++i) {
            S += acc_slots[i * 16];
            C += (long long)((const unsigned int*)acc_slots)[i * 16 + 1];
        }
        out[0] = (C > 0) ? (S / (float)C) : 0.0f;
    }
}

extern "C" void kernel_launch(void* const* d_in, const int* in_sizes, int n_in,
                              void* d_out, int out_size, void* d_ws, size_t ws_size,
                              hipStream_t stream) {
    const float* feat    = (const float*)d_in[0];
    const float* centers = (const float*)d_in[1];
    const int*   labels  = (const int*)d_in[2];
    float* out = (float*)d_out;

    char* ws = (char*)d_ws;
    float*          acc_slots = (float*)ws;                          // 256 B (4 x 64B)
    float*          t         = (float*)(ws + 1024);                 // 32 KB
    float*          corr_s    = (float*)(ws + 65536);                // 32 KB
    unsigned int*   corr_c    = (unsigned int*)(ws + 98304);         // 32 KB
    unsigned short* fb        = (unsigned short*)(ws + 131072);      // 2 MB
    unsigned short* cb        = (unsigned short*)(ws + 4*1024*1024); // 5.14 MB

    hipMemsetAsync(ws, 0, 256, stream);
    k_prep<<<NORM_BLOCKS + CONV_BLOCKS, 256, 0, stream>>>(
        feat, centers, labels, fb, cb, t, corr_s, corr_c);
    dim3 grid(NSPLIT, 32);
    k_main<<<grid, 512, 0, stream>>>(fb, cb, t, acc_slots);
    k_finalize<<<1, 256, 0, stream>>>(acc_slots, corr_s, corr_c, out);
}